// Round 3
// baseline (550.307 us; speedup 1.0000x reference)
//
#include <hip/hip_runtime.h>

typedef __attribute__((ext_vector_type(4))) float f32x4;
typedef __attribute__((ext_vector_type(8))) short bf16x8;
typedef __attribute__((ext_vector_type(4))) int i32x4;

#define SCL2 0.09016844f   /* (1/16) * log2(e) */

__device__ __forceinline__ unsigned short f2bf(float f) {
    unsigned int u = __float_as_uint(f);
    u = (u + 0x7FFFu + ((u >> 16) & 1u)) >> 16;   // RNE
    return (unsigned short)u;
}

__device__ __forceinline__ f32x4 mfma16(bf16x8 a, bf16x8 b, f32x4 c) {
    return __builtin_amdgcn_mfma_f32_16x16x32_bf16(a, b, c, 0, 0, 0);
}

__device__ __forceinline__ unsigned cvtpk(float lo, float hi) {
    unsigned r;
    asm("v_cvt_pk_bf16_f32 %0, %1, %2" : "=v"(r) : "v"(lo), "v"(hi));
    return r;
}

// ---------------- kernel 1: x + pos_emb -> bf16 ----------------
__global__ void prep_x(const float* __restrict__ x, const float* __restrict__ pos,
                       unsigned short* __restrict__ xb) {
    int t = blockIdx.x * 256 + threadIdx.x;
    int e = t * 8;
    int row  = e >> 8;
    int prow = row % 2304;
    int col  = e & 255;
    const float4* xp = (const float4*)(x + e);
    const float4* pp = (const float4*)(pos + prow * 256 + col);
    float4 a0 = xp[0], a1 = xp[1];
    float4 p0 = pp[0], p1 = pp[1];
    bf16x8 o;
    o[0] = (short)f2bf(a0.x + p0.x);  o[1] = (short)f2bf(a0.y + p0.y);
    o[2] = (short)f2bf(a0.z + p0.z);  o[3] = (short)f2bf(a0.w + p0.w);
    o[4] = (short)f2bf(a1.x + p1.x);  o[5] = (short)f2bf(a1.y + p1.y);
    o[6] = (short)f2bf(a1.z + p1.z);  o[7] = (short)f2bf(a1.w + p1.w);
    *(bf16x8*)(xb + e) = o;
}

// ---------------- kernel 2: pack weights transposed + biases ----------------
__global__ void prep_w(const float* __restrict__ wq, const float* __restrict__ wk,
                       const float* __restrict__ wv, const float* __restrict__ bq,
                       const float* __restrict__ bk, const float* __restrict__ bv,
                       unsigned short* __restrict__ wT, float* __restrict__ bias) {
    int t = blockIdx.x * 256 + threadIdx.x;
    int n = t >> 8, k = t & 255;
    const float* w = (n < 256) ? wq : (n < 512) ? wk : wv;
    int col = n & 255;
    wT[t] = f2bf(w[k * 256 + col]);
    if (t < 768) {
        const float* bs = (t < 256) ? bq : (t < 512) ? bk : bv;
        bias[t] = bs[t & 255];
    }
}

// ---------------- kernel 3: QKV GEMM ----------------
__global__ __launch_bounds__(256)
void qkv_gemm(const unsigned short* __restrict__ xb,
              const unsigned short* __restrict__ wT,
              const float* __restrict__ bias,
              unsigned short* __restrict__ qb,
              unsigned short* __restrict__ kb,
              unsigned short* __restrict__ vtb) {
    __shared__ __align__(16) unsigned short Al[64 * 64];
    __shared__ __align__(16) unsigned short Bl[64 * 64];
    int rm0 = blockIdx.y * 64;
    int bn0 = blockIdx.x * 64;
    int tid = threadIdx.x;
    int lane = tid & 63, w = tid >> 6;
    int l15 = lane & 15, l4 = lane >> 4;

    f32x4 acc[4] = {};
    for (int k0 = 0; k0 < 256; k0 += 64) {
        __syncthreads();
        #pragma unroll
        for (int i = 0; i < 2; ++i) {
            int c = i * 256 + tid;
            int r = c >> 3, cc = c & 7;
            i32x4 av = *(const i32x4*)(xb + (long)(rm0 + r) * 256 + k0 + cc * 8);
            *(i32x4*)((char*)Al + r * 128 + ((cc * 16) ^ ((r & 7) << 4))) = av;
            i32x4 bv = *(const i32x4*)(wT + (long)(bn0 + r) * 256 + k0 + cc * 8);
            *(i32x4*)((char*)Bl + r * 128 + ((cc * 16) ^ ((r & 7) << 4))) = bv;
        }
        __syncthreads();
        int arow = w * 16 + l15;
        #pragma unroll
        for (int kk = 0; kk < 2; ++kk) {
            bf16x8 a = *(const bf16x8*)((char*)Al + arow * 128 +
                        ((kk * 64 + l4 * 16) ^ ((arow & 7) << 4)));
            #pragma unroll
            for (int nb = 0; nb < 4; ++nb) {
                int brow = nb * 16 + l15;
                bf16x8 b = *(const bf16x8*)((char*)Bl + brow * 128 +
                            ((kk * 64 + l4 * 16) ^ ((brow & 7) << 4)));
                acc[nb] = mfma16(a, b, acc[nb]);
            }
        }
    }
    int bidx  = rm0 / 2304;
    int grow0 = rm0 + w * 16 + l4 * 4;
    int srow0 = grow0 - bidx * 2304;
    #pragma unroll
    for (int nb = 0; nb < 4; ++nb) {
        int n = bn0 + nb * 16 + l15;
        float bs = bias[n];
        unsigned short h0 = f2bf(acc[nb][0] + bs);
        unsigned short h1 = f2bf(acc[nb][1] + bs);
        unsigned short h2 = f2bf(acc[nb][2] + bs);
        unsigned short h3 = f2bf(acc[nb][3] + bs);
        if (n < 256) {
            qb[(long)(grow0 + 0) * 256 + n] = h0;
            qb[(long)(grow0 + 1) * 256 + n] = h1;
            qb[(long)(grow0 + 2) * 256 + n] = h2;
            qb[(long)(grow0 + 3) * 256 + n] = h3;
        } else if (n < 512) {
            int nn = n - 256;
            kb[(long)(grow0 + 0) * 256 + nn] = h0;
            kb[(long)(grow0 + 1) * 256 + nn] = h1;
            kb[(long)(grow0 + 2) * 256 + nn] = h2;
            kb[(long)(grow0 + 3) * 256 + nn] = h3;
        } else {
            ushort4 pk4;
            pk4.x = h0; pk4.y = h1; pk4.z = h2; pk4.w = h3;
            *(ushort4*)(vtb + ((long)bidx * 256 + (n - 512)) * 2304 + srow0) = pk4;
        }
    }
}

// ---------------- kernel 4: flash attention ----------------
// 1152 blocks (72 q-tiles x 16 batches), 256 thr = 4 waves.
// waves (wq, g): wq = q-subtile (16 rows), g = KV half.  In-block flash combine.
__global__ __launch_bounds__(256, 3)
void attn(const unsigned short* __restrict__ qb,
          const unsigned short* __restrict__ kbuf,
          const unsigned short* __restrict__ vtb,
          float* __restrict__ out) {
    __shared__ __align__(16) char Kl[2][16384];   // [group][32 kv x 512B], swizzled
    __shared__ float Ml[4][16];
    __shared__ float Ll[4][16];

    int orig = blockIdx.x;
    int L = (orig & 7) * 144 + (orig >> 3);   // XCD-chunked: 2 batches per XCD
    int b  = L / 72;
    int q0 = (L % 72) * 32;

    int tid = threadIdx.x;
    int lane = tid & 63, w = tid >> 6;
    int wq = w & 1, g = w >> 1;
    int l15 = lane & 15, l4 = lane >> 4;

    const char* kgB = (const char*)kbuf + ((size_t)b * 2304 + (size_t)g * 1152) * 512;
    const unsigned short* vg0 = vtb + (size_t)b * 256 * 2304;

    // async stage of one 32x256 K tile (16KB) into Kl[g], pre-swizzled source
    auto stage = [&](int kv0) {
        #pragma unroll
        for (int i = 0; i < 8; ++i) {
            int chunk = wq * 8 + i;
            int kvr = chunk * 2 + (lane >> 5);
            int slot = lane & 31;
            const char* src = kgB + (size_t)(kv0 + kvr) * 512 + ((slot * 16) ^ ((kvr & 7) << 4));
            __builtin_amdgcn_global_load_lds(
                (const __attribute__((address_space(1))) unsigned int*)src,
                (__attribute__((address_space(3))) unsigned int*)(&Kl[g][chunk * 1024]),
                16, 0, 0);
        }
    };

    stage(0);

    // Q fragments (B-operand layout): q-row = l15, d = kbk*32 + l4*8
    bf16x8 qf[8];
    {
        const unsigned short* qrow = qb + ((size_t)b * 2304 + q0 + wq * 16 + l15) * 256;
        #pragma unroll
        for (int kbk = 0; kbk < 8; ++kbk)
            qf[kbk] = *(const bf16x8*)(qrow + kbk * 32 + l4 * 8);
    }

    f32x4 o[16] = {};
    float m = -__builtin_inff(), l = 0.f;

    for (int t = 0; t < 36; ++t) {
        __syncthreads();                       // stage(t) landed
        // S^T = K Q  (swapped): lane holds S[q=l15][kv = cb*16 + l4*4 + j]
        f32x4 s[2] = {};
        const char* kb_ = Kl[g];
        #pragma unroll
        for (int kbk = 0; kbk < 8; ++kbk) {
            #pragma unroll
            for (int cb = 0; cb < 2; ++cb) {
                int row = cb * 16 + l15;
                bf16x8 kf = *(const bf16x8*)(kb_ + row * 512 +
                             ((kbk * 64 + l4 * 16) ^ ((row & 7) << 4)));
                s[cb] = mfma16(kf, qf[kbk], s[cb]);
            }
        }
        __syncthreads();                       // Kl reads done
        if (t < 35) stage((t + 1) * 32);       // async: overlaps softmax+PV

        // in-register online softmax (log2 domain)
        float p[8];
        #pragma unroll
        for (int cb = 0; cb < 2; ++cb)
            #pragma unroll
            for (int j = 0; j < 4; ++j)
                p[cb * 4 + j] = s[cb][j] * SCL2;
        float mx = fmaxf(fmaxf(fmaxf(p[0], p[1]), fmaxf(p[2], p[3])),
                         fmaxf(fmaxf(p[4], p[5]), fmaxf(p[6], p[7])));
        mx = fmaxf(mx, __shfl_xor(mx, 16));
        mx = fmaxf(mx, __shfl_xor(mx, 32));
        float mn = fmaxf(m, mx);
        float rs = 0.f;
        #pragma unroll
        for (int i = 0; i < 8; ++i) { p[i] = exp2f(p[i] - mn); rs += p[i]; }
        rs += __shfl_xor(rs, 16);
        rs += __shfl_xor(rs, 32);
        float alpha = exp2f(m - mn);
        l = l * alpha + rs;
        bool resc = (mn > m);
        m = mn;
        if (__any(resc)) {                     // defer-rescale
            #pragma unroll
            for (int j = 0; j < 4; ++j) {
                float ao = __shfl(alpha, l4 * 4 + j);
                #pragma unroll
                for (int nb = 0; nb < 16; ++nb) o[nb][j] *= ao;
            }
        }

        // P -> bf16 A-frag in-register (cvt_pk + bpermute), no LDS round-trip
        unsigned pk00 = cvtpk(p[0], p[1]);
        unsigned pk01 = cvtpk(p[2], p[3]);
        unsigned pk10 = cvtpk(p[4], p[5]);
        unsigned pk11 = cvtpk(p[6], p[7]);
        int srcA = (((l4 * 2) & 3) << 4) | l15;
        int srcB = (((l4 * 2 + 1) & 3) << 4) | l15;
        int A0 = __shfl((int)pk00, srcA), A1 = __shfl((int)pk01, srcA);
        int B0 = __shfl((int)pk10, srcA), B1 = __shfl((int)pk11, srcA);
        int C0 = __shfl((int)pk00, srcB), C1 = __shfl((int)pk01, srcB);
        int D0 = __shfl((int)pk10, srcB), D1 = __shfl((int)pk11, srcB);
        bool hi2 = (l4 >= 2);
        i32x4 pw;
        pw[0] = hi2 ? B0 : A0;
        pw[1] = hi2 ? B1 : A1;
        pw[2] = hi2 ? D0 : C0;
        pw[3] = hi2 ? D1 : C1;
        bf16x8 pf = *(bf16x8*)&pw;

        // O += P V, V B-frags straight from L2 (vtb is [d][s])
        int kvg = g * 1152 + t * 32;
        #pragma unroll
        for (int nb = 0; nb < 16; ++nb) {
            bf16x8 vf = *(const bf16x8*)(vg0 + (size_t)(nb * 16 + l15) * 2304 + kvg + l4 * 8);
            o[nb] = mfma16(pf, vf, o[nb]);
        }
    }

    // ---- in-block flash combine of the two KV halves ----
    __syncthreads();
    if (lane < 16) { Ml[w][lane] = m; Ll[w][lane] = l; }
    float* Obuf = (float*)Kl;                  // reuse 32KB: [wq][16 q][256 d]
    if (g == 1) {
        #pragma unroll
        for (int nb = 0; nb < 16; ++nb)
            #pragma unroll
            for (int j = 0; j < 4; ++j)
                Obuf[wq * 4096 + (l4 * 4 + j) * 256 + nb * 16 + l15] = o[nb][j];
    }
    __syncthreads();
    if (g == 0) {
        float a0[4], a1[4];
        #pragma unroll
        for (int j = 0; j < 4; ++j) {
            int q = l4 * 4 + j;
            float m0 = Ml[wq][q],     l0 = Ll[wq][q];
            float m1 = Ml[wq + 2][q], l1 = Ll[wq + 2][q];
            float mxx = fmaxf(m0, m1);
            float e0 = exp2f(m0 - mxx), e1 = exp2f(m1 - mxx);
            float li = 1.0f / (l0 * e0 + l1 * e1);
            a0[j] = e0 * li; a1[j] = e1 * li;
        }
        size_t obase = ((size_t)b * 2304 + q0 + wq * 16) * 256;
        #pragma unroll
        for (int nb = 0; nb < 16; ++nb)
            #pragma unroll
            for (int j = 0; j < 4; ++j) {
                float o1 = Obuf[wq * 4096 + (l4 * 4 + j) * 256 + nb * 16 + l15];
                out[obase + (size_t)(l4 * 4 + j) * 256 + nb * 16 + l15] =
                    o[nb][j] * a0[j] + o1 * a1[j];
            }
    }
}

extern "C" void kernel_launch(void* const* d_in, const int* in_sizes, int n_in,
                              void* d_out, int out_size, void* d_ws, size_t ws_size,
                              hipStream_t stream) {
    const float* x   = (const float*)d_in[0];
    const float* wq  = (const float*)d_in[1];
    const float* bq  = (const float*)d_in[2];
    const float* wk  = (const float*)d_in[3];
    const float* bk  = (const float*)d_in[4];
    const float* wv  = (const float*)d_in[5];
    const float* bv  = (const float*)d_in[6];
    const float* pos = (const float*)d_in[7];

    const long NROW = 36864;            // 16*2304
    unsigned short* xb  = (unsigned short*)d_ws;
    unsigned short* qbf = xb  + NROW * 256;
    unsigned short* kbf = qbf + NROW * 256;
    unsigned short* vtb = kbf + NROW * 256;
    unsigned short* wT  = vtb + NROW * 256;
    float* bias = (float*)(wT + 768 * 256);

    prep_x<<<4608, 256, 0, stream>>>(x, pos, xb);
    prep_w<<<768, 256, 0, stream>>>(wq, wk, wv, bq, bk, bv, wT, bias);
    qkv_gemm<<<dim3(12, 576), 256, 0, stream>>>(xb, wT, bias, qbf, kbf, vtb);
    attn<<<1152, 256, 0, stream>>>(qbf, kbf, vtb, (float*)d_out);
}

// Round 5
// 291.993 us; speedup vs baseline: 1.8847x; 1.8847x over previous
//
#include <hip/hip_runtime.h>

typedef __attribute__((ext_vector_type(4))) float f32x4;
typedef __attribute__((ext_vector_type(8))) short bf16x8;
typedef __attribute__((ext_vector_type(4))) int i32x4;
typedef __attribute__((ext_vector_type(2))) unsigned int u32x2;

#define SCL2 0.09016844f   /* (1/16) * log2(e) */

__device__ __forceinline__ unsigned short f2bf(float f) {
    unsigned int u = __float_as_uint(f);
    u = (u + 0x7FFFu + ((u >> 16) & 1u)) >> 16;   // RNE
    return (unsigned short)u;
}

__device__ __forceinline__ f32x4 mfma16(bf16x8 a, bf16x8 b, f32x4 c) {
    return __builtin_amdgcn_mfma_f32_16x16x32_bf16(a, b, c, 0, 0, 0);
}

__device__ __forceinline__ unsigned cvtpk(float lo, float hi) {
    unsigned r;
    asm("v_cvt_pk_bf16_f32 %0, %1, %2" : "=v"(r) : "v"(lo), "v"(hi));
    return r;
}

// permlane swaps via builtins (SSA results -> no register-aliasing hazard).
__device__ __forceinline__ void pl32swap(unsigned &a, unsigned &b) {
#if __has_builtin(__builtin_amdgcn_permlane32_swap)
    u32x2 r = __builtin_amdgcn_permlane32_swap(a, b, false, false);
    a = r[0]; b = r[1];
#else
    asm volatile("v_permlane32_swap_b32 %0, %1" : "+v"(a), "+&v"(b));
#endif
}
__device__ __forceinline__ void pl16swap(unsigned &a, unsigned &b) {
#if __has_builtin(__builtin_amdgcn_permlane16_swap)
    u32x2 r = __builtin_amdgcn_permlane16_swap(a, b, false, false);
    a = r[0]; b = r[1];
#else
    asm volatile("v_permlane16_swap_b32 %0, %1" : "+v"(a), "+&v"(b));
#endif
}

// reduce x across the four 16-lane rows (same l15, all l4) — max / sum
__device__ __forceinline__ float redmax4(float x) {
    unsigned a = __float_as_uint(x), b = a;
    pl32swap(a, b);
    x = fmaxf(__uint_as_float(a), __uint_as_float(b));
    a = __float_as_uint(x); b = a;
    pl16swap(a, b);
    return fmaxf(__uint_as_float(a), __uint_as_float(b));
}
__device__ __forceinline__ float redsum4(float x) {
    unsigned a = __float_as_uint(x), b = a;
    pl32swap(a, b);
    x = __uint_as_float(a) + __uint_as_float(b);
    a = __float_as_uint(x); b = a;
    pl16swap(a, b);
    return __uint_as_float(a) + __uint_as_float(b);
}

// ---------------- kernel 1: x + pos_emb -> bf16 ----------------
__global__ void prep_x(const float* __restrict__ x, const float* __restrict__ pos,
                       unsigned short* __restrict__ xb) {
    int t = blockIdx.x * 256 + threadIdx.x;
    int e = t * 8;
    int row  = e >> 8;
    int prow = row % 2304;
    int col  = e & 255;
    const float4* xp = (const float4*)(x + e);
    const float4* pp = (const float4*)(pos + prow * 256 + col);
    float4 a0 = xp[0], a1 = xp[1];
    float4 p0 = pp[0], p1 = pp[1];
    bf16x8 o;
    o[0] = (short)f2bf(a0.x + p0.x);  o[1] = (short)f2bf(a0.y + p0.y);
    o[2] = (short)f2bf(a0.z + p0.z);  o[3] = (short)f2bf(a0.w + p0.w);
    o[4] = (short)f2bf(a1.x + p1.x);  o[5] = (short)f2bf(a1.y + p1.y);
    o[6] = (short)f2bf(a1.z + p1.z);  o[7] = (short)f2bf(a1.w + p1.w);
    *(bf16x8*)(xb + e) = o;
}

// ---------------- kernel 2: pack weights transposed + biases ----------------
__global__ void prep_w(const float* __restrict__ wq, const float* __restrict__ wk,
                       const float* __restrict__ wv, const float* __restrict__ bq,
                       const float* __restrict__ bk, const float* __restrict__ bv,
                       unsigned short* __restrict__ wT, float* __restrict__ bias) {
    int t = blockIdx.x * 256 + threadIdx.x;
    int n = t >> 8, k = t & 255;
    const float* w = (n < 256) ? wq : (n < 512) ? wk : wv;
    int col = n & 255;
    wT[t] = f2bf(w[k * 256 + col]);
    if (t < 768) {
        const float* bs = (t < 256) ? bq : (t < 512) ? bk : bv;
        bias[t] = bs[t & 255];
    }
}

// ---------------- kernel 3: QKV GEMM (128x128, BK=64, global_load_lds) ----------
__global__ __launch_bounds__(256)
void qkv_gemm(const unsigned short* __restrict__ xb,
              const unsigned short* __restrict__ wT,
              const float* __restrict__ bias,
              unsigned short* __restrict__ qb,
              unsigned short* __restrict__ kb,
              unsigned short* __restrict__ vtb) {
    __shared__ __align__(16) char Al[16384];   // [128 rows][128B], swizzled
    __shared__ __align__(16) char Bl[16384];
    int rm0 = blockIdx.y * 128;
    int bn0 = blockIdx.x * 128;
    int tid = threadIdx.x;
    int lane = tid & 63, w = tid >> 6;
    int wr = w >> 1, wc = w & 1;
    int l15 = lane & 15, l4 = lane >> 4;

    int soff[4];
    {
        int h = lane >> 3, s8 = lane & 7;
        #pragma unroll
        for (int i = 0; i < 4; ++i) {
            int lr = w * 32 + i * 8 + h;
            soff[i] = lr * 512 + ((s8 * 16) ^ ((lr & 7) << 4));
        }
    }
    const char* aB = (const char*)xb + (size_t)rm0 * 512;
    const char* bB = (const char*)wT + (size_t)bn0 * 512;

    f32x4 acc[4][4] = {};
    for (int k0 = 0; k0 < 256; k0 += 64) {
        __syncthreads();
        #pragma unroll
        for (int i = 0; i < 4; ++i) {
            __builtin_amdgcn_global_load_lds(
                (const __attribute__((address_space(1))) unsigned int*)(aB + k0 * 2 + soff[i]),
                (__attribute__((address_space(3))) unsigned int*)(Al + w * 4096 + i * 1024),
                16, 0, 0);
            __builtin_amdgcn_global_load_lds(
                (const __attribute__((address_space(1))) unsigned int*)(bB + k0 * 2 + soff[i]),
                (__attribute__((address_space(3))) unsigned int*)(Bl + w * 4096 + i * 1024),
                16, 0, 0);
        }
        __syncthreads();
        #pragma unroll
        for (int kk = 0; kk < 2; ++kk) {
            bf16x8 af[4], bfr[4];
            #pragma unroll
            for (int mb = 0; mb < 4; ++mb) {
                int ar = wr * 64 + mb * 16 + l15;
                af[mb] = *(const bf16x8*)(Al + ar * 128 +
                          ((kk * 64 + l4 * 16) ^ ((ar & 7) << 4)));
            }
            #pragma unroll
            for (int nb = 0; nb < 4; ++nb) {
                int br = wc * 64 + nb * 16 + l15;
                bfr[nb] = *(const bf16x8*)(Bl + br * 128 +
                           ((kk * 64 + l4 * 16) ^ ((br & 7) << 4)));
            }
            #pragma unroll
            for (int mb = 0; mb < 4; ++mb)
                #pragma unroll
                for (int nb = 0; nb < 4; ++nb)
                    acc[mb][nb] = mfma16(af[mb], bfr[nb], acc[mb][nb]);
        }
    }
    int bidx = rm0 / 2304;                    // 2304 = 18*128
    #pragma unroll
    for (int mb = 0; mb < 4; ++mb) {
        int grow0 = rm0 + wr * 64 + mb * 16 + l4 * 4;
        int srow0 = grow0 - bidx * 2304;
        #pragma unroll
        for (int nb = 0; nb < 4; ++nb) {
            int n = bn0 + wc * 64 + nb * 16 + l15;
            float bs = bias[n];
            unsigned short h0 = f2bf(acc[mb][nb][0] + bs);
            unsigned short h1 = f2bf(acc[mb][nb][1] + bs);
            unsigned short h2 = f2bf(acc[mb][nb][2] + bs);
            unsigned short h3 = f2bf(acc[mb][nb][3] + bs);
            if (n < 256) {
                qb[(long)(grow0 + 0) * 256 + n] = h0;
                qb[(long)(grow0 + 1) * 256 + n] = h1;
                qb[(long)(grow0 + 2) * 256 + n] = h2;
                qb[(long)(grow0 + 3) * 256 + n] = h3;
            } else if (n < 512) {
                int nn = n - 256;
                kb[(long)(grow0 + 0) * 256 + nn] = h0;
                kb[(long)(grow0 + 1) * 256 + nn] = h1;
                kb[(long)(grow0 + 2) * 256 + nn] = h2;
                kb[(long)(grow0 + 3) * 256 + nn] = h3;
            } else {
                ushort4 pk4;
                pk4.x = h0; pk4.y = h1; pk4.z = h2; pk4.w = h3;
                *(ushort4*)(vtb + ((long)bidx * 256 + (n - 512)) * 2304 + srow0) = pk4;
            }
        }
    }
}

// ---------------- kernel 4: flash attention ----------------
// 576 blocks (36 q-tiles x 16 b), XCD-swizzled. 4 waves; wave = 16 q rows.
// KVBLK=32; K+V^T double-buffered in LDS via global_load_lds (64 KB).
__global__ __launch_bounds__(256, 2)
void attn(const unsigned short* __restrict__ qb,
          const unsigned short* __restrict__ kbuf,
          const unsigned short* __restrict__ vtb,
          float* __restrict__ out) {
    // [0,32K): Kl[2][32 rows][512B swz]; [32K,64K): Vl[2][256 rows][64B swz]
    __shared__ __align__(16) char lds[65536];

    int orig = blockIdx.x;
    int L = (orig & 7) * 72 + (orig >> 3);    // 576 = 8*72 exact, bijective
    int b = L / 36, q0 = (L % 36) * 64;

    int tid = threadIdx.x;
    int lane = tid & 63, w = tid >> 6;
    int l15 = lane & 15, l4 = lane >> 4;

    const char* kgB = (const char*)(kbuf + (size_t)b * 2304 * 256);
    const unsigned short* vgB = vtb + (size_t)b * 256 * 2304;

    int koff[4], voff[4];
    {
        int h = lane >> 5, slot = lane & 31;
        #pragma unroll
        for (int i = 0; i < 4; ++i) {
            int lr = w * 8 + i * 2 + h;                    // local kv row 0..31
            koff[i] = lr * 512 + ((slot * 16) ^ ((lr & 7) << 4));
        }
        int s4 = lane & 3;
        #pragma unroll
        for (int i = 0; i < 4; ++i) {
            int dr = w * 64 + i * 16 + (lane >> 2);        // d row 0..255
            int g = s4 ^ ((dr >> 1) & 3);                  // kv-group involution
            voff[i] = dr * 2304 + g * 8;                   // elements
        }
    }

    auto stage = [&](int kv0, int buf) {
        char* kdst = lds + buf * 16384 + w * 4096;
        const char* ksrc = kgB + (size_t)kv0 * 512;
        #pragma unroll
        for (int i = 0; i < 4; ++i)
            __builtin_amdgcn_global_load_lds(
                (const __attribute__((address_space(1))) unsigned int*)(ksrc + koff[i]),
                (__attribute__((address_space(3))) unsigned int*)(kdst + i * 1024),
                16, 0, 0);
        char* vdst = lds + 32768 + buf * 16384 + w * 4096;
        #pragma unroll
        for (int i = 0; i < 4; ++i)
            __builtin_amdgcn_global_load_lds(
                (const __attribute__((address_space(1))) unsigned int*)(vgB + kv0 + voff[i]),
                (__attribute__((address_space(3))) unsigned int*)(vdst + i * 1024),
                16, 0, 0);
    };

    stage(0, 0);

    // Q fragments (B-operand): q-row = l15 (wave's 16 rows), d = kbk*32 + l4*8
    bf16x8 qf[8];
    {
        const unsigned short* qrow = qb + ((size_t)b * 2304 + q0 + w * 16 + l15) * 256;
        #pragma unroll
        for (int kbk = 0; kbk < 8; ++kbk)
            qf[kbk] = *(const bf16x8*)(qrow + kbk * 32 + l4 * 8);
    }

    f32x4 o[16] = {};
    float m = -__builtin_inff(), l = 0.f;
    int vslot = (l4 ^ ((l15 >> 1) & 3)) * 16;

    for (int t = 0; t < 72; ++t) {
        __syncthreads();                       // stage(t) landed; buf^1 reads done
        if (t < 71) stage((t + 1) * 32, (t + 1) & 1);

        // S^T = K Q: lane holds S[q=l15][kv = cb*16 + l4*4 + j]
        const char* kl = lds + (t & 1) * 16384;
        f32x4 s[2] = {};
        #pragma unroll
        for (int kbk = 0; kbk < 8; ++kbk) {
            #pragma unroll
            for (int cb = 0; cb < 2; ++cb) {
                int row = cb * 16 + l15;
                bf16x8 kf = *(const bf16x8*)(kl + row * 512 +
                             ((kbk * 64 + l4 * 16) ^ ((row & 7) << 4)));
                s[cb] = mfma16(kf, qf[kbk], s[cb]);
            }
        }

        // in-register online softmax (log2 domain), permlane reductions
        float p[8];
        #pragma unroll
        for (int cb = 0; cb < 2; ++cb)
            #pragma unroll
            for (int j = 0; j < 4; ++j)
                p[cb * 4 + j] = s[cb][j] * SCL2;
        float mx = fmaxf(fmaxf(fmaxf(p[0], p[1]), fmaxf(p[2], p[3])),
                         fmaxf(fmaxf(p[4], p[5]), fmaxf(p[6], p[7])));
        mx = redmax4(mx);
        if (__any(mx > m + 8.f)) {             // defer-rescale (THR=8, log2 units)
            float mn = fmaxf(m, mx);
            float alpha = exp2f(m - mn);
            float aj[4];
            #pragma unroll
            for (int j = 0; j < 4; ++j) aj[j] = __shfl(alpha, l4 * 4 + j);
            #pragma unroll
            for (int nb = 0; nb < 16; ++nb)
                #pragma unroll
                for (int j = 0; j < 4; ++j) o[nb][j] *= aj[j];
            l *= alpha;
            m = mn;
        }
        float rs = 0.f;
        #pragma unroll
        for (int i = 0; i < 8; ++i) { p[i] = exp2f(p[i] - m); rs += p[i]; }
        l += redsum4(rs);

        // P -> A-frag: 4 cvt_pk + 2x swap32 + 2x swap16 (no LDS crossbar)
        unsigned c0 = cvtpk(p[0], p[1]);
        unsigned c1 = cvtpk(p[2], p[3]);
        unsigned c2 = cvtpk(p[4], p[5]);
        unsigned c3 = cvtpk(p[6], p[7]);
        pl32swap(c0, c2);
        pl32swap(c1, c3);
        pl16swap(c0, c2);
        pl16swap(c1, c3);
        i32x4 pw; pw[0] = (int)c0; pw[1] = (int)c1; pw[2] = (int)c2; pw[3] = (int)c3;
        bf16x8 pf = *(bf16x8*)&pw;

        // O += P V from LDS V^T tile
        const char* vl = lds + 32768 + (t & 1) * 16384;
        #pragma unroll
        for (int nb = 0; nb < 16; ++nb) {
            bf16x8 vf = *(const bf16x8*)(vl + (nb * 16 + l15) * 64 + vslot);
            o[nb] = mfma16(pf, vf, o[nb]);
        }
    }

    // epilogue
    float linv[4];
    #pragma unroll
    for (int j = 0; j < 4; ++j) linv[j] = 1.0f / __shfl(l, l4 * 4 + j);
    size_t obase = ((size_t)b * 2304 + q0 + w * 16) * 256;
    #pragma unroll
    for (int nb = 0; nb < 16; ++nb)
        #pragma unroll
        for (int j = 0; j < 4; ++j)
            out[obase + (size_t)(l4 * 4 + j) * 256 + nb * 16 + l15] = o[nb][j] * linv[j];
}

extern "C" void kernel_launch(void* const* d_in, const int* in_sizes, int n_in,
                              void* d_out, int out_size, void* d_ws, size_t ws_size,
                              hipStream_t stream) {
    const float* x   = (const float*)d_in[0];
    const float* wq  = (const float*)d_in[1];
    const float* bq  = (const float*)d_in[2];
    const float* wk  = (const float*)d_in[3];
    const float* bk  = (const float*)d_in[4];
    const float* wv  = (const float*)d_in[5];
    const float* bv  = (const float*)d_in[6];
    const float* pos = (const float*)d_in[7];

    const long NROW = 36864;            // 16*2304
    unsigned short* xb  = (unsigned short*)d_ws;
    unsigned short* qbf = xb  + NROW * 256;
    unsigned short* kbf = qbf + NROW * 256;
    unsigned short* vtb = kbf + NROW * 256;
    unsigned short* wT  = vtb + NROW * 256;
    float* bias = (float*)(wT + 768 * 256);

    prep_x<<<4608, 256, 0, stream>>>(x, pos, xb);
    prep_w<<<768, 256, 0, stream>>>(wq, wk, wv, bq, bk, bv, wT, bias);
    qkv_gemm<<<dim3(6, 288), 256, 0, stream>>>(xb, wT, bias, qbf, kbf, vtb);
    attn<<<576, 256, 0, stream>>>(qbf, kbf, vtb, (float*)d_out);
}

// Round 8
// 288.412 us; speedup vs baseline: 1.9081x; 1.0124x over previous
//
#include <hip/hip_runtime.h>

typedef __attribute__((ext_vector_type(4))) float f32x4;
typedef __attribute__((ext_vector_type(8))) short bf16x8;
typedef __attribute__((ext_vector_type(4))) int i32x4;
typedef __attribute__((ext_vector_type(2))) unsigned int u32x2;

#define SCL2 0.09016844f   /* (1/16) * log2(e) */

__device__ __forceinline__ unsigned short f2bf(float f) {
    unsigned int u = __float_as_uint(f);
    u = (u + 0x7FFFu + ((u >> 16) & 1u)) >> 16;   // RNE
    return (unsigned short)u;
}

__device__ __forceinline__ f32x4 mfma16(bf16x8 a, bf16x8 b, f32x4 c) {
    return __builtin_amdgcn_mfma_f32_16x16x32_bf16(a, b, c, 0, 0, 0);
}

__device__ __forceinline__ unsigned cvtpk(float lo, float hi) {
    unsigned r;
    asm("v_cvt_pk_bf16_f32 %0, %1, %2" : "=v"(r) : "v"(lo), "v"(hi));
    return r;
}

__device__ __forceinline__ void pl32swap(unsigned &a, unsigned &b) {
#if __has_builtin(__builtin_amdgcn_permlane32_swap)
    u32x2 r = __builtin_amdgcn_permlane32_swap(a, b, false, false);
    a = r[0]; b = r[1];
#else
    asm volatile("v_permlane32_swap_b32 %0, %1" : "+v"(a), "+&v"(b));
#endif
}
__device__ __forceinline__ void pl16swap(unsigned &a, unsigned &b) {
#if __has_builtin(__builtin_amdgcn_permlane16_swap)
    u32x2 r = __builtin_amdgcn_permlane16_swap(a, b, false, false);
    a = r[0]; b = r[1];
#else
    asm volatile("v_permlane16_swap_b32 %0, %1" : "+v"(a), "+&v"(b));
#endif
}

__device__ __forceinline__ float redmax4(float x) {
    unsigned a = __float_as_uint(x), b = a;
    pl32swap(a, b);
    x = fmaxf(__uint_as_float(a), __uint_as_float(b));
    a = __float_as_uint(x); b = a;
    pl16swap(a, b);
    return fmaxf(__uint_as_float(a), __uint_as_float(b));
}
__device__ __forceinline__ float redsum4(float x) {
    unsigned a = __float_as_uint(x), b = a;
    pl32swap(a, b);
    x = __uint_as_float(a) + __uint_as_float(b);
    a = __float_as_uint(x); b = a;
    pl16swap(a, b);
    return __uint_as_float(a) + __uint_as_float(b);
}

// online softmax for one 16-row q-subtile + pack P to bf16 A-frag
__device__ __forceinline__ bf16x8 softmax_pack(const f32x4 (&s)[2], float &m, float &l,
                                               f32x4 (&o)[16], int l4) {
    float p[8];
    #pragma unroll
    for (int cb = 0; cb < 2; ++cb)
        #pragma unroll
        for (int j = 0; j < 4; ++j)
            p[cb * 4 + j] = s[cb][j] * SCL2;
    float mx = fmaxf(fmaxf(fmaxf(p[0], p[1]), fmaxf(p[2], p[3])),
                     fmaxf(fmaxf(p[4], p[5]), fmaxf(p[6], p[7])));
    mx = redmax4(mx);
    if (__any(mx > m + 8.f)) {                 // defer-rescale
        float mn = fmaxf(m, mx);
        float alpha = __builtin_amdgcn_exp2f(m - mn);
        float aj[4];
        #pragma unroll
        for (int j = 0; j < 4; ++j) aj[j] = __shfl(alpha, l4 * 4 + j);
        #pragma unroll
        for (int nb = 0; nb < 16; ++nb)
            #pragma unroll
            for (int j = 0; j < 4; ++j) o[nb][j] *= aj[j];
        l *= alpha; m = mn;
    }
    float rs = 0.f;
    #pragma unroll
    for (int i = 0; i < 8; ++i) { p[i] = __builtin_amdgcn_exp2f(p[i] - m); rs += p[i]; }
    l += redsum4(rs);
    unsigned c0 = cvtpk(p[0], p[1]);
    unsigned c1 = cvtpk(p[2], p[3]);
    unsigned c2 = cvtpk(p[4], p[5]);
    unsigned c3 = cvtpk(p[6], p[7]);
    pl32swap(c0, c2); pl32swap(c1, c3);
    pl16swap(c0, c2); pl16swap(c1, c3);
    i32x4 pw; pw[0] = (int)c0; pw[1] = (int)c1; pw[2] = (int)c2; pw[3] = (int)c3;
    return *(bf16x8*)&pw;
}

// ---------------- kernel 1: x + pos_emb -> bf16 ----------------
__global__ void prep_x(const float* __restrict__ x, const float* __restrict__ pos,
                       unsigned short* __restrict__ xb) {
    int t = blockIdx.x * 256 + threadIdx.x;
    int e = t * 8;
    int row  = e >> 8;
    int prow = row % 2304;
    int col  = e & 255;
    const float4* xp = (const float4*)(x + e);
    const float4* pp = (const float4*)(pos + prow * 256 + col);
    float4 a0 = xp[0], a1 = xp[1];
    float4 p0 = pp[0], p1 = pp[1];
    bf16x8 o;
    o[0] = (short)f2bf(a0.x + p0.x);  o[1] = (short)f2bf(a0.y + p0.y);
    o[2] = (short)f2bf(a0.z + p0.z);  o[3] = (short)f2bf(a0.w + p0.w);
    o[4] = (short)f2bf(a1.x + p1.x);  o[5] = (short)f2bf(a1.y + p1.y);
    o[6] = (short)f2bf(a1.z + p1.z);  o[7] = (short)f2bf(a1.w + p1.w);
    *(bf16x8*)(xb + e) = o;
}

// ---------------- kernel 2: pack weights transposed + biases ----------------
__global__ void prep_w(const float* __restrict__ wq, const float* __restrict__ wk,
                       const float* __restrict__ wv, const float* __restrict__ bq,
                       const float* __restrict__ bk, const float* __restrict__ bv,
                       unsigned short* __restrict__ wT, float* __restrict__ bias) {
    int t = blockIdx.x * 256 + threadIdx.x;
    int n = t >> 8, k = t & 255;
    const float* w = (n < 256) ? wq : (n < 512) ? wk : wv;
    int col = n & 255;
    wT[t] = f2bf(w[k * 256 + col]);
    if (t < 768) {
        const float* bs = (t < 256) ? bq : (t < 512) ? bk : bv;
        bias[t] = bs[t & 255];
    }
}

// ---------------- kernel 3: QKV GEMM (128x128, BK=64, global_load_lds) ----------
__global__ __launch_bounds__(256)
void qkv_gemm(const unsigned short* __restrict__ xb,
              const unsigned short* __restrict__ wT,
              const float* __restrict__ bias,
              unsigned short* __restrict__ qb,
              unsigned short* __restrict__ kb,
              unsigned short* __restrict__ vtb) {
    __shared__ __align__(16) char Al[16384];   // [128 rows][128B], swizzled
    __shared__ __align__(16) char Bl[16384];
    int rm0 = blockIdx.y * 128;
    int bn0 = blockIdx.x * 128;
    int tid = threadIdx.x;
    int lane = tid & 63, w = tid >> 6;
    int wr = w >> 1, wc = w & 1;
    int l15 = lane & 15, l4 = lane >> 4;

    int soff[4];
    {
        int h = lane >> 3, s8 = lane & 7;
        #pragma unroll
        for (int i = 0; i < 4; ++i) {
            int lr = w * 32 + i * 8 + h;
            soff[i] = lr * 512 + ((s8 * 16) ^ ((lr & 7) << 4));
        }
    }
    const char* aB = (const char*)xb + (size_t)rm0 * 512;
    const char* bB = (const char*)wT + (size_t)bn0 * 512;

    f32x4 acc[4][4] = {};
    for (int k0 = 0; k0 < 256; k0 += 64) {
        __syncthreads();
        #pragma unroll
        for (int i = 0; i < 4; ++i) {
            __builtin_amdgcn_global_load_lds(
                (const __attribute__((address_space(1))) unsigned int*)(aB + k0 * 2 + soff[i]),
                (__attribute__((address_space(3))) unsigned int*)(Al + w * 4096 + i * 1024),
                16, 0, 0);
            __builtin_amdgcn_global_load_lds(
                (const __attribute__((address_space(1))) unsigned int*)(bB + k0 * 2 + soff[i]),
                (__attribute__((address_space(3))) unsigned int*)(Bl + w * 4096 + i * 1024),
                16, 0, 0);
        }
        __syncthreads();
        #pragma unroll
        for (int kk = 0; kk < 2; ++kk) {
            bf16x8 af[4], bfr[4];
            #pragma unroll
            for (int mb = 0; mb < 4; ++mb) {
                int ar = wr * 64 + mb * 16 + l15;
                af[mb] = *(const bf16x8*)(Al + ar * 128 +
                          ((kk * 64 + l4 * 16) ^ ((ar & 7) << 4)));
            }
            #pragma unroll
            for (int nb = 0; nb < 4; ++nb) {
                int br = wc * 64 + nb * 16 + l15;
                bfr[nb] = *(const bf16x8*)(Bl + br * 128 +
                           ((kk * 64 + l4 * 16) ^ ((br & 7) << 4)));
            }
            #pragma unroll
            for (int mb = 0; mb < 4; ++mb)
                #pragma unroll
                for (int nb = 0; nb < 4; ++nb)
                    acc[mb][nb] = mfma16(af[mb], bfr[nb], acc[mb][nb]);
        }
    }
    int bidx = rm0 / 2304;                    // 2304 = 18*128
    #pragma unroll
    for (int mb = 0; mb < 4; ++mb) {
        int grow0 = rm0 + wr * 64 + mb * 16 + l4 * 4;
        int srow0 = grow0 - bidx * 2304;
        #pragma unroll
        for (int nb = 0; nb < 4; ++nb) {
            int n = bn0 + wc * 64 + nb * 16 + l15;
            float bs = bias[n];
            unsigned short h0 = f2bf(acc[mb][nb][0] + bs);
            unsigned short h1 = f2bf(acc[mb][nb][1] + bs);
            unsigned short h2 = f2bf(acc[mb][nb][2] + bs);
            unsigned short h3 = f2bf(acc[mb][nb][3] + bs);
            if (n < 256) {
                qb[(long)(grow0 + 0) * 256 + n] = h0;
                qb[(long)(grow0 + 1) * 256 + n] = h1;
                qb[(long)(grow0 + 2) * 256 + n] = h2;
                qb[(long)(grow0 + 3) * 256 + n] = h3;
            } else if (n < 512) {
                int nn = n - 256;
                kb[(long)(grow0 + 0) * 256 + nn] = h0;
                kb[(long)(grow0 + 1) * 256 + nn] = h1;
                kb[(long)(grow0 + 2) * 256 + nn] = h2;
                kb[(long)(grow0 + 3) * 256 + nn] = h3;
            } else {
                ushort4 pk4;
                pk4.x = h0; pk4.y = h1; pk4.z = h2; pk4.w = h3;
                *(ushort4*)(vtb + ((long)bidx * 256 + (n - 512)) * 2304 + srow0) = pk4;
            }
        }
    }
}

// ---------------- kernel 4: flash attention, split-KV, 32 q-rows/wave ----------
// 576 blocks = 16 b x 18 q-tiles(128) x 2 kv-halves, XCD-swizzled.
// 4 waves; wave = 32 q rows (2 subtiles). KVBLK=32, K+V dbuf in LDS (64 KB).
__global__ __launch_bounds__(256, 2)
void attn(const unsigned short* __restrict__ qb,
          const unsigned short* __restrict__ kbuf,
          const unsigned short* __restrict__ vtb,
          float* __restrict__ po0, float* __restrict__ po1,
          float2* __restrict__ ml) {
    // [0,32K): Kl[2][32 rows][512B swz]; [32K,64K): Vl[2][256 rows][64B swz]
    __shared__ __align__(16) char lds[65536];

    int orig = blockIdx.x;
    int L = (orig & 7) * 72 + (orig >> 3);    // 576 = 8*72 exact, bijective
    int b = L / 36;
    int rem = L - b * 36;
    int qt = rem >> 1, half = rem & 1;
    int q0 = qt * 128;

    int tid = threadIdx.x;
    int lane = tid & 63, w = tid >> 6;
    int l15 = lane & 15, l4 = lane >> 4;

    const char* kgB = (const char*)kbuf + ((size_t)b * 2304 + half * 1152) * 512;
    const unsigned short* vgB = vtb + (size_t)b * 256 * 2304 + half * 1152;

    int koff[4], voff[4];
    {
        int h = lane >> 5, slot = lane & 31;
        #pragma unroll
        for (int i = 0; i < 4; ++i) {
            int lr = w * 8 + i * 2 + h;                    // local kv row 0..31
            koff[i] = lr * 512 + ((slot * 16) ^ ((lr & 7) << 4));
        }
        int s4 = lane & 3;
        #pragma unroll
        for (int i = 0; i < 4; ++i) {
            int dr = w * 64 + i * 16 + (lane >> 2);        // d row 0..255
            int g = s4 ^ ((dr >> 1) & 3);                  // kv-group involution
            voff[i] = dr * 2304 + g * 8;                   // elements
        }
    }

    auto stage = [&](int kv0, int buf) {
        char* kdst = lds + buf * 16384 + w * 4096;
        const char* ksrc = kgB + (size_t)kv0 * 512;
        #pragma unroll
        for (int i = 0; i < 4; ++i)
            __builtin_amdgcn_global_load_lds(
                (const __attribute__((address_space(1))) unsigned int*)(ksrc + koff[i]),
                (__attribute__((address_space(3))) unsigned int*)(kdst + i * 1024),
                16, 0, 0);
        char* vdst = lds + 32768 + buf * 16384 + w * 4096;
        #pragma unroll
        for (int i = 0; i < 4; ++i)
            __builtin_amdgcn_global_load_lds(
                (const __attribute__((address_space(1))) unsigned int*)(vgB + kv0 + voff[i]),
                (__attribute__((address_space(3))) unsigned int*)(vdst + i * 1024),
                16, 0, 0);
    };

    stage(0, 0);

    // Q fragments for two 16-row subtiles
    bf16x8 qfA[8], qfB[8];
    {
        const unsigned short* qrowA = qb + ((size_t)b * 2304 + q0 + w * 32 + l15) * 256;
        const unsigned short* qrowB = qrowA + 16 * 256;
        #pragma unroll
        for (int kbk = 0; kbk < 8; ++kbk) {
            qfA[kbk] = *(const bf16x8*)(qrowA + kbk * 32 + l4 * 8);
            qfB[kbk] = *(const bf16x8*)(qrowB + kbk * 32 + l4 * 8);
        }
    }

    f32x4 oA[16] = {}, oB[16] = {};
    float mA = -__builtin_inff(), lA = 0.f;
    float mB = -__builtin_inff(), lB = 0.f;
    int vslot = (l4 ^ ((l15 >> 1) & 3)) * 16;

    for (int t = 0; t < 36; ++t) {
        __syncthreads();                       // stage(t) landed; buf^1 reads done
        if (t < 35) stage((t + 1) * 32, (t + 1) & 1);

        // S^T = K Q for both q-subtiles; each kf read feeds 2 MFMAs
        const char* kl = lds + (t & 1) * 16384;
        f32x4 sA[2] = {}, sB[2] = {};
        #pragma unroll
        for (int kbk = 0; kbk < 8; ++kbk) {
            #pragma unroll
            for (int cb = 0; cb < 2; ++cb) {
                int row = cb * 16 + l15;
                bf16x8 kf = *(const bf16x8*)(kl + row * 512 +
                             ((kbk * 64 + l4 * 16) ^ ((row & 7) << 4)));
                sA[cb] = mfma16(kf, qfA[kbk], sA[cb]);
                sB[cb] = mfma16(kf, qfB[kbk], sB[cb]);
            }
        }

        bf16x8 pfA = softmax_pack(sA, mA, lA, oA, l4);
        bf16x8 pfB = softmax_pack(sB, mB, lB, oB, l4);

        // O += P V; each vf read feeds 2 MFMAs
        const char* vl = lds + 32768 + (t & 1) * 16384;
        #pragma unroll
        for (int nb = 0; nb < 16; ++nb) {
            bf16x8 vf = *(const bf16x8*)(vl + (nb * 16 + l15) * 64 + vslot);
            oA[nb] = mfma16(pfA, vf, oA[nb]);
            oB[nb] = mfma16(pfB, vf, oB[nb]);
        }
    }

    // epilogue: raw partial O + (m,l) per q-row
    float* po = half ? po1 : po0;
    size_t rowA = (size_t)b * 2304 + q0 + w * 32;
    size_t pb = rowA * 256;
    #pragma unroll
    for (int nb = 0; nb < 16; ++nb)
        #pragma unroll
        for (int j = 0; j < 4; ++j)
            po[pb + (size_t)(l4 * 4 + j) * 256 + nb * 16 + l15] = oA[nb][j];
    pb = (rowA + 16) * 256;
    #pragma unroll
    for (int nb = 0; nb < 16; ++nb)
        #pragma unroll
        for (int j = 0; j < 4; ++j)
            po[pb + (size_t)(l4 * 4 + j) * 256 + nb * 16 + l15] = oB[nb][j];
    if (l4 == 0) {
        int mlbase = half * 36864 + (int)rowA;
        ml[mlbase + l15]      = make_float2(mA, lA);
        ml[mlbase + 16 + l15] = make_float2(mB, lB);
    }
}

// ---------------- kernel 5: combine the two KV halves ----------------
__global__ void combine(float* __restrict__ po0, const float* __restrict__ po1,
                        const float2* __restrict__ ml) {
    int t = blockIdx.x * 256 + threadIdx.x;    // 1179648 threads, 8 elems each
    int q = t >> 5;
    int d0 = (t & 31) * 8;
    float2 h0 = ml[q], h1 = ml[36864 + q];
    float mT = fmaxf(h0.x, h1.x);
    float w0 = __builtin_amdgcn_exp2f(h0.x - mT);
    float w1 = __builtin_amdgcn_exp2f(h1.x - mT);
    float inv = 1.f / (w0 * h0.y + w1 * h1.y);
    w0 *= inv; w1 *= inv;
    size_t base = (size_t)q * 256 + d0;
    f32x4 a0 = *(const f32x4*)(po0 + base);
    f32x4 a1 = *(const f32x4*)(po0 + base + 4);
    f32x4 b0 = *(const f32x4*)(po1 + base);
    f32x4 b1 = *(const f32x4*)(po1 + base + 4);
    *(f32x4*)(po0 + base)     = a0 * w0 + b0 * w1;
    *(f32x4*)(po0 + base + 4) = a1 * w0 + b1 * w1;
}

extern "C" void kernel_launch(void* const* d_in, const int* in_sizes, int n_in,
                              void* d_out, int out_size, void* d_ws, size_t ws_size,
                              hipStream_t stream) {
    const float* x   = (const float*)d_in[0];
    const float* wq  = (const float*)d_in[1];
    const float* bq  = (const float*)d_in[2];
    const float* wk  = (const float*)d_in[3];
    const float* bk  = (const float*)d_in[4];
    const float* wv  = (const float*)d_in[5];
    const float* bv  = (const float*)d_in[6];
    const float* pos = (const float*)d_in[7];

    const long NROW = 36864;            // 16*2304
    // ws layout: qbf | kbf | vtb | wT | bias | xb ... po1 overlays xb (xb dead
    // after qkv_gemm) and extends past it | ml.  Total ~95.4 MB.
    unsigned short* qbf = (unsigned short*)d_ws;
    unsigned short* kbf = qbf + NROW * 256;
    unsigned short* vtb = kbf + NROW * 256;
    unsigned short* wT  = vtb + NROW * 256;
    float* bias = (float*)(wT + 768 * 256);
    unsigned short* xb  = (unsigned short*)(bias + 768);
    float* po1 = (float*)xb;                       // overlay, 37.75 MB
    float2* ml = (float2*)(po1 + NROW * 256);      // 0.59 MB

    prep_x<<<4608, 256, 0, stream>>>(x, pos, xb);
    prep_w<<<768, 256, 0, stream>>>(wq, wk, wv, bq, bk, bv, wT, bias);
    qkv_gemm<<<dim3(6, 288), 256, 0, stream>>>(xb, wT, bias, qbf, kbf, vtb);
    attn<<<576, 256, 0, stream>>>(qbf, kbf, vtb, (float*)d_out, po1, ml);
    combine<<<4608, 256, 0, stream>>>((float*)d_out, po1, ml);
}